// Round 16
// baseline (806.856 us; speedup 1.0000x reference)
//
#include <hip/hip_runtime.h>

#define N_TOK 32768
#define D_ 512
#define F_ 2048
#define E_ 8
#define M_TILE 64
#define NSLOT_MAX 66560   // 65536 + 8*128 padding, 128-aligned per expert

typedef __attribute__((ext_vector_type(8))) short bf16x8;
typedef __attribute__((ext_vector_type(8))) unsigned short us8;
typedef __attribute__((ext_vector_type(16))) float f32x16;

__device__ __forceinline__ unsigned short f2bf(float f) {
  union { float f; unsigned u; } v; v.f = f;
  unsigned r = v.u + 0x7fffu + ((v.u >> 16) & 1u);   // RNE; inputs finite
  return (unsigned short)(r >> 16);
}

__device__ __forceinline__ void gload16(const void* g, void* l) {
  __builtin_amdgcn_global_load_lds((const __attribute__((address_space(1))) void*)g,
                                   (__attribute__((address_space(3))) void*)l, 16, 0, 0);
}

// lgkm-only barrier: LDS ordering without draining vmcnt.
__device__ __forceinline__ void lbar() {
  asm volatile("s_waitcnt lgkmcnt(0)" ::: "memory");
  __builtin_amdgcn_s_barrier();
}

// W1 [E][D][F] f32 -> 32x32x16-frag bf16 W1F [E][fb(F/32)][ks(D/16)][64 l][8 j]:
// lane l holds W1[e][ks*16+(l>>5)*8+j][fb*32+(l&31)]
__global__ void cvtW1_k(const float* __restrict__ W1, unsigned short* __restrict__ W1F) {
  const int gw = blockIdx.x * 4 + (threadIdx.x >> 6);   // 16384 waves
  const int l  = threadIdx.x & 63;
  const int ks = gw & 31;
  const int fb = (gw >> 5) & 63;
  const int e  = gw >> 11;
  const int f  = fb * 32 + (l & 31);
  const int k0 = ks * 16 + (l >> 5) * 8;
  const float* src = W1 + ((size_t)e * D_ + k0) * F_ + f;
  us8 v;
#pragma unroll
  for (int j = 0; j < 8; ++j) v[j] = f2bf(src[(size_t)j * F_]);
  *reinterpret_cast<us8*>(W1F + ((size_t)gw * 64 + l) * 8) = v;
}

// W2 [E][F][D] f32 -> 32x32x16-frag bf16 W2B [E][kf(F/16)][db(D/32)][64 l][8 j]:
// lane l holds W2[e][kf*16+(l>>5)*8+j][db*32+(l&31)]
__global__ void cvtW2_k(const float* __restrict__ W2, unsigned short* __restrict__ W2B) {
  const int gw = blockIdx.x * 4 + (threadIdx.x >> 6);   // 16384 waves
  const int l  = threadIdx.x & 63;
  const int db = gw & 15;
  const int kf = (gw >> 4) & 127;
  const int e  = gw >> 11;
  const int d  = db * 32 + (l & 31);
  const int f0 = kf * 16 + (l >> 5) * 8;
  const float* src = W2 + ((size_t)e * F_ + f0) * D_ + d;
  us8 v;
#pragma unroll
  for (int j = 0; j < 8; ++j) v[j] = f2bf(src[(size_t)j * D_]);
  *reinterpret_cast<us8*>(W2B + ((size_t)gw * 64 + l) * 8) = v;
}

// one wave per token: logits = x_row @ Wr, softmax fp32, top-2. NO atomics.
__global__ void router_k(const float* __restrict__ x, const float* __restrict__ Wr,
                         int* __restrict__ ridx, float* __restrict__ rw) {
  const int wid = threadIdx.x >> 6, lane = threadIdx.x & 63;
  const int t = blockIdx.x * 4 + wid;
  const float* xr = x + (size_t)t * D_ + lane * 8;
  const float4 xa = *reinterpret_cast<const float4*>(xr);
  const float4 xb = *reinterpret_cast<const float4*>(xr + 4);
  float xv[8] = {xa.x, xa.y, xa.z, xa.w, xb.x, xb.y, xb.z, xb.w};
  float lg[8] = {0, 0, 0, 0, 0, 0, 0, 0};
#pragma unroll
  for (int j = 0; j < 8; ++j) {
    const float* wr = Wr + (size_t)(lane * 8 + j) * E_;
    float4 w0 = *reinterpret_cast<const float4*>(wr);
    float4 w1 = *reinterpret_cast<const float4*>(wr + 4);
    lg[0] += xv[j] * w0.x; lg[1] += xv[j] * w0.y; lg[2] += xv[j] * w0.z; lg[3] += xv[j] * w0.w;
    lg[4] += xv[j] * w1.x; lg[5] += xv[j] * w1.y; lg[6] += xv[j] * w1.z; lg[7] += xv[j] * w1.w;
  }
#pragma unroll
  for (int off = 32; off; off >>= 1) {
#pragma unroll
    for (int q = 0; q < 8; ++q) lg[q] += __shfl_xor(lg[q], off);
  }
  if (lane == 0) {
    float m = lg[0];
#pragma unroll
    for (int q = 1; q < 8; ++q) m = fmaxf(m, lg[q]);
    float p[8]; float s = 0.f;
#pragma unroll
    for (int q = 0; q < 8; ++q) { p[q] = expf(lg[q] - m); s += p[q]; }
    float inv = 1.f / s;
    int e1 = 0;
#pragma unroll
    for (int q = 1; q < 8; ++q) if (p[q] > p[e1]) e1 = q;
    int e2 = (e1 == 0) ? 1 : 0;
#pragma unroll
    for (int q = 0; q < 8; ++q) { if (q == e1) continue; if (p[q] > p[e2]) e2 = q; }
    ridx[2 * t] = e1; ridx[2 * t + 1] = e2;
    rw[2 * t] = p[e1] * inv; rw[2 * t + 1] = p[e2] * inv;
  }
}

// single block: counts, 128-padded offsets, zero cursors
__global__ void count_k(const int* __restrict__ ridx, int* __restrict__ ctrl) {
  __shared__ int h[E_];
  const int tid = threadIdx.x;   // 1024
  if (tid < E_) h[tid] = 0;
  __syncthreads();
  int c0=0,c1=0,c2=0,c3=0,c4=0,c5=0,c6=0,c7=0;
  for (int i = tid; i < 2 * N_TOK; i += 1024) {
    int v = ridx[i];
    c0 += (v == 0); c1 += (v == 1); c2 += (v == 2); c3 += (v == 3);
    c4 += (v == 4); c5 += (v == 5); c6 += (v == 6); c7 += (v == 7);
  }
  atomicAdd(&h[0], c0); atomicAdd(&h[1], c1); atomicAdd(&h[2], c2); atomicAdd(&h[3], c3);
  atomicAdd(&h[4], c4); atomicAdd(&h[5], c5); atomicAdd(&h[6], c6); atomicAdd(&h[7], c7);
  __syncthreads();
  if (tid == 0) {
    int a = 0;
    for (int e = 0; e < E_; ++e) {
      ctrl[e] = h[e];
      ctrl[8 + e] = a;
      a += (h[e] + 127) & ~127;
      ctrl[16 + e] = 0;
    }
    ctrl[24] = a;
  }
}

// per-block LDS ranks + 8 global atomics per block
__global__ void scatter_k(const int* __restrict__ ridx, const float* __restrict__ rw,
                          int* __restrict__ ctrl, int* __restrict__ ptok,
                          float* __restrict__ pgate) {
  __shared__ int h[E_], base[E_];
  const int tid = threadIdx.x;                 // 512
  const int g = blockIdx.x * 512 + tid;        // entry id
  if (tid < E_) h[tid] = 0;
  __syncthreads();
  const int e = ridx[g];
  const int r = atomicAdd(&h[e], 1);           // LDS atomic
  __syncthreads();
  if (tid < E_) base[tid] = atomicAdd(&ctrl[16 + tid], h[tid]);
  __syncthreads();
  const int pos = ctrl[8 + e] + base[e] + r;
  ptok[pos] = g >> 1;
  pgate[pos] = rw[g];
}

// gathered activations, 32x32x16-frag: XpF[sb(32 rows)][ks(D/16)][64 l][8 j]:
// lane l holds x[tok(sb*32 + (l&31))][ks*16 + (l>>5)*8 + j]. Pad slots -> 0.
__global__ void gather_k(const float* __restrict__ x, const int* __restrict__ ptok,
                         const int* __restrict__ ctrl, unsigned short* __restrict__ XpF) {
  const int sb = blockIdx.x * 4 + (threadIdx.x >> 6);   // 2080 slot-blocks of 32
  const int l  = threadIdx.x & 63;
  const int slot = sb * 32 + (l & 31);
  bool valid = false;
#pragma unroll
  for (int e = 0; e < E_; ++e) {
    int off = ctrl[8 + e], c = ctrl[e];
    valid = valid || (slot >= off && slot < off + c);
  }
  const int tok = valid ? ptok[slot] : 0;
  const int j0 = (l >> 5) * 8;
  unsigned short* dst = XpF + (size_t)sb * 16384 + l * 8;
#pragma unroll
  for (int ks = 0; ks < 32; ++ks) {
    us8 v = (us8){0, 0, 0, 0, 0, 0, 0, 0};
    if (valid) {
      const float* src = x + (size_t)tok * D_ + ks * 16 + j0;
      float4 a = *reinterpret_cast<const float4*>(src);
      float4 b = *reinterpret_cast<const float4*>(src + 4);
      v[0] = f2bf(a.x); v[1] = f2bf(a.y); v[2] = f2bf(a.z); v[3] = f2bf(a.w);
      v[4] = f2bf(b.x); v[5] = f2bf(b.y); v[6] = f2bf(b.z); v[7] = f2bf(b.w);
    }
    *reinterpret_cast<us8*>(dst + (size_t)ks * 512) = v;
  }
}

// 32x32x16, wave owns 64 f (2 f-blocks, BF=512, 4 jF iters): each af LDS read
// feeds 4 MFMAs -> LDS floor ~184us < MFMA floor ~220us (R13 was LDS-bound at
// 410us floor). Xs 64KB + Hs[64][512] 64KB single-buffered (2 lgkm barriers x
// 4 iters). G1: 1-group-ahead bw rotation; G2: 4-deep b2 ring (fixes R15's
// exposed L2 latency). Weight frags read once per block. e = gid&7 affinity.
#define MFMA32(A, B, C) __builtin_amdgcn_mfma_f32_32x32x16_bf16(A, B, C, 0, 0, 0)

__global__ __launch_bounds__(512, 2) void ffn_k(
    const unsigned short* __restrict__ XpF,
    const unsigned short* __restrict__ W1F,   // [E][F/32][D/16][64][8]
    const unsigned short* __restrict__ W2B,   // [E][F/16][D/32][64][8]
    const int* __restrict__ ptok, const float* __restrict__ pgate,
    const int* __restrict__ ctrl, float* __restrict__ out) {
  const int gid = blockIdx.x;
  const int e = gid & 7;                      // XCD + expert affinity
  const int cnt = ctrl[e];
  const int tile0 = (gid >> 3) * M_TILE;
  if (tile0 >= cnt) return;
  const int slot0 = ctrl[8 + e] + tile0;      // 64-aligned
  const int sb0 = slot0 >> 5;                 // 32-row block index (even)

  __shared__ unsigned short Xs[32768];        // 64 KB: [mb(2)][ks(32)][64][8]
  __shared__ unsigned short Hs[32768];        // 64 KB: [64 rows][512 f] swizzled

  const int tid = threadIdx.x;
  const int wn = tid >> 6, lane = tid & 63;   // 8 waves
  const int l5 = lane >> 5, l31 = lane & 31;

  const unsigned short* w1e = W1F + (size_t)e * (F_ * D_);
  const unsigned short* W2e = W2B + (size_t)e * (F_ * D_);

  // ---- prologue: stage X panel (64 KB linear DMA)
  {
    const char* xsrc = (const char*)(XpF + (size_t)sb0 * 16384);
#pragma unroll
    for (int i = 0; i < 8; ++i) {
      const int o = (i * 512 + tid) * 16;
      gload16(xsrc + o, (char*)Xs + o);
    }
  }
  asm volatile("s_waitcnt vmcnt(0)" ::: "memory");
  __builtin_amdgcn_s_barrier();

  f32x16 acc[2][2];                           // [mb][db]
#pragma unroll
  for (int i = 0; i < 2; ++i)
#pragma unroll
    for (int j = 0; j < 2; ++j)
#pragma unroll
      for (int r = 0; r < 16; ++r) acc[i][j][r] = 0.f;

  for (int jF = 0; jF < F_; jF += 512) {      // 4 iters
    // G1: wave's f-blocks fb = jF/32 + wn*2 + {0,1}; fb stride 16384 ushorts
    const unsigned short* w1b = w1e + ((size_t)((jF >> 5) + wn * 2) * 32) * 512 + lane * 8;
    // G2: kf base jF/16, wave's d-blocks wn*2 + {0,1}; kf stride 8192 ushorts
    const unsigned short* w2b = W2e + ((size_t)((jF >> 4) * 16 + wn * 2)) * 512 + lane * 8;

    f32x16 hacc[2][2];                        // [mb][fi]
#pragma unroll
    for (int i = 0; i < 2; ++i)
#pragma unroll
      for (int j = 0; j < 2; ++j)
#pragma unroll
        for (int r = 0; r < 16; ++r) hacc[i][j][r] = 0.f;

    bf16x8 bwA[2][4], bwB[2][4];              // [fi][i] rotation buffers
    bf16x8 ring[4][2];                        // G2 b2 ring [slot][db]

    // load group 0 (ks 0..3, both f-blocks)
#pragma unroll
    for (int i = 0; i < 4; ++i) {
      bwA[0][i] = *reinterpret_cast<const bf16x8*>(w1b + (size_t)i * 512);
      bwA[1][i] = *reinterpret_cast<const bf16x8*>(w1b + (size_t)(16384 + i * 512));
    }

    __builtin_amdgcn_s_setprio(1);
#pragma unroll
    for (int g = 0; g < 8; ++g) {             // 8 groups of 4 ks
      // load group g+1 into the other buffer (or fill G2 ring at g==7)
      if (g < 7) {
#pragma unroll
        for (int i = 0; i < 4; ++i) {
          bf16x8 v0 = *reinterpret_cast<const bf16x8*>(w1b + (size_t)((g + 1) * 4 + i) * 512);
          bf16x8 v1 = *reinterpret_cast<const bf16x8*>(w1b + (size_t)(16384 + ((g + 1) * 4 + i) * 512));
          if (g & 1) { bwA[0][i] = v0; bwA[1][i] = v1; }
          else       { bwB[0][i] = v0; bwB[1][i] = v1; }
        }
      } else {
#pragma unroll
        for (int s = 0; s < 4; ++s)
#pragma unroll
          for (int db = 0; db < 2; ++db)
            ring[s][db] = *reinterpret_cast<const bf16x8*>(w2b + (size_t)(s * 8192 + db * 512));
      }
      // consume group g
#pragma unroll
      for (int i = 0; i < 4; ++i) {
        const int ks = g * 4 + i;
        bf16x8 af0 = *reinterpret_cast<const bf16x8*>(&Xs[(size_t)ks * 512 + lane * 8]);
        bf16x8 af1 = *reinterpret_cast<const bf16x8*>(&Xs[16384 + (size_t)ks * 512 + lane * 8]);
        bf16x8 c0 = (g & 1) ? bwB[0][i] : bwA[0][i];
        bf16x8 c1 = (g & 1) ? bwB[1][i] : bwA[1][i];
        hacc[0][0] = MFMA32(af0, c0, hacc[0][0]);
        hacc[0][1] = MFMA32(af0, c1, hacc[0][1]);
        hacc[1][0] = MFMA32(af1, c0, hacc[1][0]);
        hacc[1][1] = MFMA32(af1, c1, hacc[1][1]);
      }
    }
    __builtin_amdgcn_s_setprio(0);

    // ---- fast GELU -> Hs, 16B-chunk XOR swizzle (ch = (col>>3) ^ (row&15))
    // C/D layout: col(f)=l31, row = (r&3) + 8*(r>>2) + 4*l5 (+ mb*32)
#pragma unroll
    for (int mb = 0; mb < 2; ++mb)
#pragma unroll
      for (int fi = 0; fi < 2; ++fi)
#pragma unroll
        for (int r = 0; r < 16; ++r) {
          float v = hacc[mb][fi][r];
          float u = v * v;
          float wv = v * fmaf(0.044715f, u, 1.0f);
          float z = __expf(-1.5957691216057308f * wv);
          float g = v * __builtin_amdgcn_rcpf(1.0f + z);
          const int row = mb * 32 + (r & 3) + 8 * (r >> 2) + 4 * l5;
          const int col = wn * 64 + fi * 32 + l31;
          const int ch = (col >> 3) ^ (row & 15);
          Hs[row * 512 + ch * 8 + (col & 7)] = f2bf(g);
        }

    lbar();   // Hs writes visible; vmcnt NOT drained (ring loads in flight OK)

    // ---- G2: 32 kf steps, A from Hs (swizzled b128), 4-deep b2 ring
    __builtin_amdgcn_s_setprio(1);
#pragma unroll
    for (int kf = 0; kf < 32; ++kf) {
      bf16x8 bc0 = ring[kf & 3][0];
      bf16x8 bc1 = ring[kf & 3][1];
      bf16x8 ah[2];
#pragma unroll
      for (int mb = 0; mb < 2; ++mb) {
        const int row = mb * 32 + l31;
        const int cs = (kf * 2 + l5) ^ (row & 15);
        ah[mb] = *reinterpret_cast<const bf16x8*>(&Hs[row * 512 + cs * 8]);
      }
      acc[0][0] = MFMA32(ah[0], bc0, acc[0][0]);
      acc[0][1] = MFMA32(ah[0], bc1, acc[0][1]);
      acc[1][0] = MFMA32(ah[1], bc0, acc[1][0]);
      acc[1][1] = MFMA32(ah[1], bc1, acc[1][1]);
      if (kf < 28) {
#pragma unroll
        for (int db = 0; db < 2; ++db)
          ring[kf & 3][db] = *reinterpret_cast<const bf16x8*>(w2b + (size_t)((kf + 4) * 8192 + db * 512));
      }
    }
    __builtin_amdgcn_s_setprio(0);

    lbar();   // all Hs reads done before next iter's GELU overwrites
  }

  // ---- epilogue: gate from global, atomic-add (exactly 2 adds/elem -> deterministic)
  const int rowLim = cnt - tile0;
#pragma unroll
  for (int mb = 0; mb < 2; ++mb) {
#pragma unroll
    for (int r = 0; r < 16; ++r) {
      const int row = mb * 32 + (r & 3) + 8 * (r >> 2) + 4 * l5;
      if (row < rowLim) {
        const int tok = ptok[slot0 + row];
        const float gt = pgate[slot0 + row];
        float* orow = out + (size_t)tok * D_ + wn * 64 + l31;
        atomicAdd(orow, gt * acc[mb][0][r]);
        atomicAdd(orow + 32, gt * acc[mb][1][r]);
      }
    }
  }
}

extern "C" void kernel_launch(void* const* d_in, const int* in_sizes, int n_in,
                              void* d_out, int out_size, void* d_ws, size_t ws_size,
                              hipStream_t stream) {
  const float* x  = (const float*)d_in[0];
  const float* Wr = (const float*)d_in[1];
  const float* W1 = (const float*)d_in[2];
  const float* W2 = (const float*)d_in[3];
  float* out = (float*)d_out;

  char* w = (char*)d_ws;
  unsigned short* W1F = (unsigned short*)(w);                    // 16 MiB frag-ordered
  unsigned short* W2B = (unsigned short*)(w + 16777216);         // 16 MiB frag-ordered
  unsigned short* XpF = (unsigned short*)(w + 33554432);         // 65 MiB frag-ordered
  int*   ridx  = (int*)  (w + 101711872);
  float* rwgt  = (float*)(w + 101974016);
  int*   ptok  = (int*)  (w + 102236160);
  float* pgate = (float*)(w + 102502400);
  int*   ctrl  = (int*)  (w + 102768640);

  cvtW1_k<<<4096, 256, 0, stream>>>(W1, W1F);
  cvtW2_k<<<4096, 256, 0, stream>>>(W2, W2B);
  router_k<<<N_TOK / 4, 256, 0, stream>>>(x, Wr, ridx, rwgt);
  count_k<<<1, 1024, 0, stream>>>(ridx, ctrl);
  scatter_k<<<N_TOK * 2 / 512, 512, 0, stream>>>(ridx, rwgt, ctrl, ptok, pgate);
  gather_k<<<NSLOT_MAX / 32 / 4, 256, 0, stream>>>(x, ptok, ctrl, XpF);
  hipMemsetAsync(out, 0, (size_t)out_size * sizeof(float), stream);
  ffn_k<<<8192, 512, 0, stream>>>(XpF, W1F, W2B, ptok, pgate, ctrl, out);
}

// Round 17
// 647.916 us; speedup vs baseline: 1.2453x; 1.2453x over previous
//
#include <hip/hip_runtime.h>

#define N_TOK 32768
#define D_ 512
#define F_ 2048
#define E_ 8
#define M_TILE 64
#define NSLOT_MAX 66560   // 65536 + 8*128 padding, 128-aligned per expert

typedef __attribute__((ext_vector_type(8))) short bf16x8;
typedef __attribute__((ext_vector_type(8))) unsigned short us8;
typedef __attribute__((ext_vector_type(4))) float f32x4;

__device__ __forceinline__ unsigned short f2bf(float f) {
  union { float f; unsigned u; } v; v.f = f;
  unsigned r = v.u + 0x7fffu + ((v.u >> 16) & 1u);   // RNE; inputs finite
  return (unsigned short)(r >> 16);
}

__device__ __forceinline__ void gload16(const void* g, void* l) {
  __builtin_amdgcn_global_load_lds((const __attribute__((address_space(1))) void*)g,
                                   (__attribute__((address_space(3))) void*)l, 16, 0, 0);
}

// lgkm-only barrier: LDS ordering without draining vmcnt.
__device__ __forceinline__ void lbar() {
  asm volatile("s_waitcnt lgkmcnt(0)" ::: "memory");
  __builtin_amdgcn_s_barrier();
}

// W1 [E][D][F] f32 -> fragment-ordered bf16 W1F [E][F/16 fb][D/32 kb][64 l][8 j]:
// lane l holds W1[e][kb*32+(l>>4)*8+j][fb*16+(l&15)]
__global__ void cvtW1_k(const float* __restrict__ W1, unsigned short* __restrict__ W1F) {
  const int gw = blockIdx.x * 4 + (threadIdx.x >> 6);   // 16384 waves
  const int l  = threadIdx.x & 63;
  const int kb = gw & 15;
  const int fb = (gw >> 4) & 127;
  const int e  = gw >> 11;
  const int f  = fb * 16 + (l & 15);
  const int k0 = kb * 32 + (l >> 4) * 8;
  const float* src = W1 + ((size_t)e * D_ + k0) * F_ + f;
  us8 v;
#pragma unroll
  for (int j = 0; j < 8; ++j) v[j] = f2bf(src[(size_t)j * F_]);
  *reinterpret_cast<us8*>(W1F + ((size_t)gw * 64 + l) * 8) = v;
}

// W2 [E][F][D] f32 -> fragment-ordered bf16:
// dest[((e*64+fb)*32+db)*512 + l*8 + j] = bf16(W2[e][fb*32+(l>>4)*8+j][db*16+(l&15)])
__global__ void cvtW2_k(const float* __restrict__ W2, unsigned short* __restrict__ W2B) {
  const int gid = blockIdx.x * 256 + threadIdx.x;    // 1,048,576 total
  const int l  = gid & 63;
  const int db = (gid >> 6) & 31;
  const int fb = (gid >> 11) & 63;
  const int e  = gid >> 17;
  const int d  = db * 16 + (l & 15);
  const int f0 = fb * 32 + (l >> 4) * 8;
  const float* src = W2 + ((size_t)e * F_ + f0) * D_ + d;
  us8 v;
#pragma unroll
  for (int j = 0; j < 8; ++j) v[j] = f2bf(src[(size_t)j * D_]);
  *reinterpret_cast<us8*>(W2B + (size_t)gid * 8) = v;
}

// one wave per token: logits = x_row @ Wr, softmax fp32, top-2. NO atomics.
__global__ void router_k(const float* __restrict__ x, const float* __restrict__ Wr,
                         int* __restrict__ ridx, float* __restrict__ rw) {
  const int wid = threadIdx.x >> 6, lane = threadIdx.x & 63;
  const int t = blockIdx.x * 4 + wid;
  const float* xr = x + (size_t)t * D_ + lane * 8;
  const float4 xa = *reinterpret_cast<const float4*>(xr);
  const float4 xb = *reinterpret_cast<const float4*>(xr + 4);
  float xv[8] = {xa.x, xa.y, xa.z, xa.w, xb.x, xb.y, xb.z, xb.w};
  float lg[8] = {0, 0, 0, 0, 0, 0, 0, 0};
#pragma unroll
  for (int j = 0; j < 8; ++j) {
    const float* wr = Wr + (size_t)(lane * 8 + j) * E_;
    float4 w0 = *reinterpret_cast<const float4*>(wr);
    float4 w1 = *reinterpret_cast<const float4*>(wr + 4);
    lg[0] += xv[j] * w0.x; lg[1] += xv[j] * w0.y; lg[2] += xv[j] * w0.z; lg[3] += xv[j] * w0.w;
    lg[4] += xv[j] * w1.x; lg[5] += xv[j] * w1.y; lg[6] += xv[j] * w1.z; lg[7] += xv[j] * w1.w;
  }
#pragma unroll
  for (int off = 32; off; off >>= 1) {
#pragma unroll
    for (int q = 0; q < 8; ++q) lg[q] += __shfl_xor(lg[q], off);
  }
  if (lane == 0) {
    float m = lg[0];
#pragma unroll
    for (int q = 1; q < 8; ++q) m = fmaxf(m, lg[q]);
    float p[8]; float s = 0.f;
#pragma unroll
    for (int q = 0; q < 8; ++q) { p[q] = expf(lg[q] - m); s += p[q]; }
    float inv = 1.f / s;
    int e1 = 0;
#pragma unroll
    for (int q = 1; q < 8; ++q) if (p[q] > p[e1]) e1 = q;
    int e2 = (e1 == 0) ? 1 : 0;
#pragma unroll
    for (int q = 0; q < 8; ++q) { if (q == e1) continue; if (p[q] > p[e2]) e2 = q; }
    ridx[2 * t] = e1; ridx[2 * t + 1] = e2;
    rw[2 * t] = p[e1] * inv; rw[2 * t + 1] = p[e2] * inv;
  }
}

// single block: counts, 128-padded offsets, zero cursors
__global__ void count_k(const int* __restrict__ ridx, int* __restrict__ ctrl) {
  __shared__ int h[E_];
  const int tid = threadIdx.x;   // 1024
  if (tid < E_) h[tid] = 0;
  __syncthreads();
  int c0=0,c1=0,c2=0,c3=0,c4=0,c5=0,c6=0,c7=0;
  for (int i = tid; i < 2 * N_TOK; i += 1024) {
    int v = ridx[i];
    c0 += (v == 0); c1 += (v == 1); c2 += (v == 2); c3 += (v == 3);
    c4 += (v == 4); c5 += (v == 5); c6 += (v == 6); c7 += (v == 7);
  }
  atomicAdd(&h[0], c0); atomicAdd(&h[1], c1); atomicAdd(&h[2], c2); atomicAdd(&h[3], c3);
  atomicAdd(&h[4], c4); atomicAdd(&h[5], c5); atomicAdd(&h[6], c6); atomicAdd(&h[7], c7);
  __syncthreads();
  if (tid == 0) {
    int a = 0;
    for (int e = 0; e < E_; ++e) {
      ctrl[e] = h[e];
      ctrl[8 + e] = a;
      a += (h[e] + 127) & ~127;
      ctrl[16 + e] = 0;
    }
    ctrl[24] = a;
  }
}

// per-block LDS ranks + 8 global atomics per block
__global__ void scatter_k(const int* __restrict__ ridx, const float* __restrict__ rw,
                          int* __restrict__ ctrl, int* __restrict__ ptok,
                          float* __restrict__ pgate) {
  __shared__ int h[E_], base[E_];
  const int tid = threadIdx.x;                 // 512
  const int g = blockIdx.x * 512 + tid;        // entry id
  if (tid < E_) h[tid] = 0;
  __syncthreads();
  const int e = ridx[g];
  const int r = atomicAdd(&h[e], 1);           // LDS atomic
  __syncthreads();
  if (tid < E_) base[tid] = atomicAdd(&ctrl[16 + tid], h[tid]);
  __syncthreads();
  const int pos = ctrl[8 + e] + base[e] + r;
  ptok[pos] = g >> 1;
  pgate[pos] = rw[g];
}

// gathered activations, FRAGMENT-ORDERED: XpF[sb][kb][64 l][8 j]:
// lane l holds x[tok(sb*16 + (l&15))][kb*32 + (l>>4)*8 + j]. Pad slots -> 0.
__global__ void gather_k(const float* __restrict__ x, const int* __restrict__ ptok,
                         const int* __restrict__ ctrl, unsigned short* __restrict__ XpF) {
  const int sb = blockIdx.x * 4 + (threadIdx.x >> 6);   // slot-block, 4160 total
  const int l  = threadIdx.x & 63;
  const int slot = sb * 16 + (l & 15);
  bool valid = false;
#pragma unroll
  for (int e = 0; e < E_; ++e) {
    int off = ctrl[8 + e], c = ctrl[e];
    valid = valid || (slot >= off && slot < off + c);
  }
  const int tok = valid ? ptok[slot] : 0;
  const int g = l >> 4;
  unsigned short* dst = XpF + ((size_t)sb * 16) * 512 + l * 8;
#pragma unroll
  for (int kb = 0; kb < 16; ++kb) {
    us8 v = (us8){0, 0, 0, 0, 0, 0, 0, 0};
    if (valid) {
      const float* src = x + (size_t)tok * D_ + kb * 32 + g * 8;
      float4 a = *reinterpret_cast<const float4*>(src);
      float4 b = *reinterpret_cast<const float4*>(src + 4);
      v[0] = f2bf(a.x); v[1] = f2bf(a.y); v[2] = f2bf(a.z); v[3] = f2bf(a.w);
      v[4] = f2bf(b.x); v[5] = f2bf(b.y); v[6] = f2bf(b.z); v[7] = f2bf(b.w);
    }
    *reinterpret_cast<us8*>(dst + (size_t)kb * 512) = v;
  }
}

// R13 dataflow with fixed G1 geometry: wave owns FOUR f-frags (64 f) so each
// af LDS read feeds 4 MFMAs (G1 LDS reads 8192 -> 2048/block; total 10240 ->
// 4096). jF step 512 (4 iters, 8 lgkm barriers total). Xs 64K + Hs[64][512]
// 64K = 128KB. All operand streams 1-ahead register rotation (static parity).
// acc+hacc = 128 AGPR, ~120 VGPR -> fits 256 unified at 2 waves/SIMD.
#define MFMA16(A, B, C) __builtin_amdgcn_mfma_f32_16x16x32_bf16(A, B, C, 0, 0, 0)

__global__ __launch_bounds__(512, 2) void ffn_k(
    const unsigned short* __restrict__ XpF,
    const unsigned short* __restrict__ W1F,   // [E][F/16][D/32][64][8]
    const unsigned short* __restrict__ W2B,   // [E][F/32][D/16][64][8]
    const int* __restrict__ ptok, const float* __restrict__ pgate,
    const int* __restrict__ ctrl, float* __restrict__ out) {
  const int gid = blockIdx.x;
  const int e = gid & 7;                      // XCD + expert affinity
  const int cnt = ctrl[e];
  const int tile0 = (gid >> 3) * M_TILE;
  if (tile0 >= cnt) return;
  const int slot0 = ctrl[8 + e] + tile0;      // 64-aligned
  const int sb0 = slot0 >> 4;

  __shared__ unsigned short Xs[32768];        // 64 KB: [mi(4)][kb(16)][64][8]
  __shared__ unsigned short Hs[32768];        // 64 KB: [64 rows][512 f] swizzled

  const int tid = threadIdx.x;
  const int wn = tid >> 6, lane = tid & 63;   // 8 waves
  const int lr = lane & 15, lg4 = lane >> 4;

  const unsigned short* w1e = W1F + (size_t)e * (F_ * D_);
  const unsigned short* W2e = W2B + (size_t)e * (F_ * D_);

  // ---- prologue: stage X panel (64 KB linear DMA) + initial W1 kb=0 frags
  {
    const char* xsrc = (const char*)(XpF + (size_t)sb0 * 8192);
#pragma unroll
    for (int i = 0; i < 8; ++i) {
      const int o = (i * 512 + tid) * 16;
      gload16(xsrc + o, (char*)Xs + o);
    }
  }
  bf16x8 bwN[4], bwP[4];                      // W1 frag rotation [fi]
  {
    const unsigned short* w1b = w1e + ((size_t)(wn * 4) * 16) * 512 + lane * 8;
#pragma unroll
    for (int fi = 0; fi < 4; ++fi)
      bwN[fi] = *reinterpret_cast<const bf16x8*>(w1b + (size_t)fi * 8192);
  }
  asm volatile("s_waitcnt vmcnt(0)" ::: "memory");
  __builtin_amdgcn_s_barrier();

  f32x4 acc[4][4];                            // [mi][ni d-frags]
#pragma unroll
  for (int i = 0; i < 4; ++i)
#pragma unroll
    for (int j = 0; j < 4; ++j) acc[i][j] = {0.f, 0.f, 0.f, 0.f};

  for (int jF = 0; jF < F_; jF += 512) {      // 4 iters
    // G1: wave's f-frags fb = jF/16 + wn*4 + fi; frag stride 8192 ushorts
    const unsigned short* w1b = w1e + ((size_t)((jF >> 4) + wn * 4) * 16) * 512 + lane * 8;
    // G2: kf chunk fb2 = jF/32 + kf; b2 frag at ((fb2*32) + wn*4 + ni)*512
    const unsigned short* w2b = W2e + ((size_t)((jF >> 5) * 32 + wn * 4)) * 512 + lane * 8;

    f32x4 hacc[4][4];                         // [mi][fi]
#pragma unroll
    for (int i = 0; i < 4; ++i)
#pragma unroll
      for (int j = 0; j < 4; ++j) hacc[i][j] = {0.f, 0.f, 0.f, 0.f};

    bf16x8 afA[4], afB[4];
    // af prefetch kb=0
#pragma unroll
    for (int mi = 0; mi < 4; ++mi)
      afA[mi] = *reinterpret_cast<const bf16x8*>(&Xs[(mi * 16 + 0) * 512 + lane * 8]);

    __builtin_amdgcn_s_setprio(1);
#pragma unroll
    for (int kb = 0; kb < 16; ++kb) {
      // prefetch af(kb+1) into the other buffer
      if (kb < 15) {
#pragma unroll
        for (int mi = 0; mi < 4; ++mi) {
          bf16x8 v = *reinterpret_cast<const bf16x8*>(&Xs[(mi * 16 + kb + 1) * 512 + lane * 8]);
          if (kb & 1) afA[mi] = v; else afB[mi] = v;
        }
      }
      // prefetch bw(kb+1) into the other buffer
      if (kb < 15) {
#pragma unroll
        for (int fi = 0; fi < 4; ++fi) {
          bf16x8 v = *reinterpret_cast<const bf16x8*>(w1b + (size_t)fi * 8192 + (kb + 1) * 512);
          if (kb & 1) bwN[fi] = v; else bwP[fi] = v;
        }
      }
      // consume kb
#pragma unroll
      for (int mi = 0; mi < 4; ++mi) {
        bf16x8 a = (kb & 1) ? afB[mi] : afA[mi];
#pragma unroll
        for (int fi = 0; fi < 4; ++fi) {
          bf16x8 b = (kb & 1) ? bwP[fi] : bwN[fi];
          hacc[mi][fi] = MFMA16(a, b, hacc[mi][fi]);
        }
      }
    }
    __builtin_amdgcn_s_setprio(0);

    // ---- issue next-phase loads NOW (ride through GELU + barrier):
    bf16x8 b2N[4], b2P[4];
#pragma unroll
    for (int ni = 0; ni < 4; ++ni)            // G2 kf=0 group
      b2N[ni] = *reinterpret_cast<const bf16x8*>(w2b + (size_t)ni * 512);
    if (jF < F_ - 512) {                      // next jF's W1 kb=0 frags
      const unsigned short* w1n = w1b + 32 * 8192;   // fb += 32
#pragma unroll
      for (int fi = 0; fi < 4; ++fi)
        bwN[fi] = *reinterpret_cast<const bf16x8*>(w1n + (size_t)fi * 8192);
    }

    // ---- fast GELU -> Hs, 16B-chunk XOR swizzle (ch ^= row&15)
#pragma unroll
    for (int mi = 0; mi < 4; ++mi)
#pragma unroll
      for (int fi = 0; fi < 4; ++fi)
#pragma unroll
        for (int r = 0; r < 4; ++r) {
          float v = hacc[mi][fi][r];
          float u = v * v;
          float wv = v * fmaf(0.044715f, u, 1.0f);
          float z = __expf(-1.5957691216057308f * wv);
          float g = v * __builtin_amdgcn_rcpf(1.0f + z);
          const int row = mi * 16 + lg4 * 4 + r;
          const int col = wn * 64 + fi * 16 + lr;
          const int ch = (col >> 3) ^ (row & 15);
          Hs[row * 512 + ch * 8 + (col & 7)] = f2bf(g);
        }

    lbar();   // Hs writes visible; vmcnt NOT drained (b2N/bwN still in flight)

    // ---- G2: 16 kf steps; ah (LDS) and b2 (global) both 1-ahead rotation
    bf16x8 ahA[4], ahB[4];
#pragma unroll
    for (int mi = 0; mi < 4; ++mi) {          // ah prefetch kf=0
      const int row = mi * 16 + lr;
      const int cs = (0 * 4 + lg4) ^ (row & 15);
      ahA[mi] = *reinterpret_cast<const bf16x8*>(&Hs[row * 512 + cs * 8]);
    }
    __builtin_amdgcn_s_setprio(1);
#pragma unroll
    for (int kf = 0; kf < 16; ++kf) {
      if (kf < 15) {
#pragma unroll
        for (int mi = 0; mi < 4; ++mi) {      // ah(kf+1)
          const int row = mi * 16 + lr;
          const int cs = ((kf + 1) * 4 + lg4) ^ (row & 15);
          bf16x8 v = *reinterpret_cast<const bf16x8*>(&Hs[row * 512 + cs * 8]);
          if (kf & 1) ahA[mi] = v; else ahB[mi] = v;
        }
#pragma unroll
        for (int ni = 0; ni < 4; ++ni) {      // b2(kf+1)
          bf16x8 v = *reinterpret_cast<const bf16x8*>(w2b + (size_t)(kf + 1) * 16384 + ni * 512);
          if (kf & 1) b2N[ni] = v; else b2P[ni] = v;
        }
      }
#pragma unroll
      for (int mi = 0; mi < 4; ++mi) {
        bf16x8 a = (kf & 1) ? ahB[mi] : ahA[mi];
#pragma unroll
        for (int ni = 0; ni < 4; ++ni) {
          bf16x8 b = (kf & 1) ? b2P[ni] : b2N[ni];
          acc[mi][ni] = MFMA16(a, b, acc[mi][ni]);
        }
      }
    }
    __builtin_amdgcn_s_setprio(0);

    lbar();   // all Hs reads done before next iter's GELU overwrites
  }

  // ---- epilogue: gate from global, atomic-add (exactly 2 adds/elem -> deterministic)
  const int rowLim = cnt - tile0;
#pragma unroll
  for (int mi = 0; mi < 4; ++mi) {
#pragma unroll
    for (int r = 0; r < 4; ++r) {
      const int row = mi * 16 + lg4 * 4 + r;
      if (row < rowLim) {
        const int tok = ptok[slot0 + row];
        const float gt = pgate[slot0 + row];
        float* orow = out + (size_t)tok * D_ + wn * 64 + lr;
#pragma unroll
        for (int ni = 0; ni < 4; ++ni)
          atomicAdd(orow + ni * 16, gt * acc[mi][ni][r]);
      }
    }
  }
}

extern "C" void kernel_launch(void* const* d_in, const int* in_sizes, int n_in,
                              void* d_out, int out_size, void* d_ws, size_t ws_size,
                              hipStream_t stream) {
  const float* x  = (const float*)d_in[0];
  const float* Wr = (const float*)d_in[1];
  const float* W1 = (const float*)d_in[2];
  const float* W2 = (const float*)d_in[3];
  float* out = (float*)d_out;

  char* w = (char*)d_ws;
  unsigned short* W1F = (unsigned short*)(w);                    // 16 MiB frag-ordered
  unsigned short* W2B = (unsigned short*)(w + 16777216);         // 16 MiB frag-ordered
  unsigned short* XpF = (unsigned short*)(w + 33554432);         // 65 MiB frag-ordered
  int*   ridx  = (int*)  (w + 101711872);
  float* rwgt  = (float*)(w + 101974016);
  int*   ptok  = (int*)  (w + 102236160);
  float* pgate = (float*)(w + 102502400);
  int*   ctrl  = (int*)  (w + 102768640);

  cvtW1_k<<<4096, 256, 0, stream>>>(W1, W1F);
  cvtW2_k<<<4096, 256, 0, stream>>>(W2, W2B);
  router_k<<<N_TOK / 4, 256, 0, stream>>>(x, Wr, ridx, rwgt);
  count_k<<<1, 1024, 0, stream>>>(ridx, ctrl);
  scatter_k<<<N_TOK * 2 / 512, 512, 0, stream>>>(ridx, rwgt, ctrl, ptok, pgate);
  gather_k<<<NSLOT_MAX / 16 / 4, 256, 0, stream>>>(x, ptok, ctrl, XpF);
  hipMemsetAsync(out, 0, (size_t)out_size * sizeof(float), stream);
  ffn_k<<<8192, 512, 0, stream>>>(XpF, W1F, W2B, ptok, pgate, ctrl, out);
}

// Round 18
// 590.631 us; speedup vs baseline: 1.3661x; 1.0970x over previous
//
#include <hip/hip_runtime.h>

#define N_TOK 32768
#define D_ 512
#define F_ 2048
#define E_ 8
#define M_TILE 64
#define NSLOT_MAX 66560   // 65536 + 8*128 padding, 128-aligned per expert

typedef __attribute__((ext_vector_type(8))) short bf16x8;
typedef __attribute__((ext_vector_type(8))) unsigned short us8;
typedef __attribute__((ext_vector_type(4))) float f32x4;

__device__ __forceinline__ unsigned short f2bf(float f) {
  union { float f; unsigned u; } v; v.f = f;
  unsigned r = v.u + 0x7fffu + ((v.u >> 16) & 1u);   // RNE; inputs finite
  return (unsigned short)(r >> 16);
}

__device__ __forceinline__ void gload16(const void* g, void* l) {
  __builtin_amdgcn_global_load_lds((const __attribute__((address_space(1))) void*)g,
                                   (__attribute__((address_space(3))) void*)l, 16, 0, 0);
}

// lgkm-only barrier: LDS ordering without draining vmcnt.
__device__ __forceinline__ void lbar() {
  asm volatile("s_waitcnt lgkmcnt(0)" ::: "memory");
  __builtin_amdgcn_s_barrier();
}

// Fused weight conversion.
// Half A (gw < 16384): W1 [E][D][F] -> W1F [E][F/16 fb][D/32 kb][64 l][8 j]
//   lane l holds W1[e][kb*32+(l>>4)*8+j][fb*16+(l&15)]
// Half B: W2 [E][F][D] -> W2B [((e*64+fb)*32+db)*512 + l*8 + j]
//   = bf16(W2[e][fb*32+(l>>4)*8+j][db*16+(l&15)])
__global__ void cvtW12_k(const float* __restrict__ W1, unsigned short* __restrict__ W1F,
                         const float* __restrict__ W2, unsigned short* __restrict__ W2B) {
  const int gw = blockIdx.x * 4 + (threadIdx.x >> 6);   // 32768 waves
  const int l  = threadIdx.x & 63;
  if (gw < 16384) {
    const int kb = gw & 15;
    const int fb = (gw >> 4) & 127;
    const int e  = gw >> 11;
    const int f  = fb * 16 + (l & 15);
    const int k0 = kb * 32 + (l >> 4) * 8;
    const float* src = W1 + ((size_t)e * D_ + k0) * F_ + f;
    us8 v;
#pragma unroll
    for (int j = 0; j < 8; ++j) v[j] = f2bf(src[(size_t)j * F_]);
    *reinterpret_cast<us8*>(W1F + ((size_t)gw * 64 + l) * 8) = v;
  } else {
    const int gw2 = gw - 16384;
    const int db = gw2 & 31;
    const int fb = (gw2 >> 5) & 63;
    const int e  = gw2 >> 11;
    const int d  = db * 16 + (l & 15);
    const int f0 = fb * 32 + (l >> 4) * 8;
    const float* src = W2 + ((size_t)e * F_ + f0) * D_ + d;
    us8 v;
#pragma unroll
    for (int j = 0; j < 8; ++j) v[j] = f2bf(src[(size_t)j * D_]);
    *reinterpret_cast<us8*>(W2B + ((size_t)gw2 * 64 + l) * 8) = v;
  }
}

// one wave per token: logits = x_row @ Wr, softmax fp32, top-2. NO atomics.
__global__ void router_k(const float* __restrict__ x, const float* __restrict__ Wr,
                         int* __restrict__ ridx, float* __restrict__ rw) {
  const int wid = threadIdx.x >> 6, lane = threadIdx.x & 63;
  const int t = blockIdx.x * 4 + wid;
  const float* xr = x + (size_t)t * D_ + lane * 8;
  const float4 xa = *reinterpret_cast<const float4*>(xr);
  const float4 xb = *reinterpret_cast<const float4*>(xr + 4);
  float xv[8] = {xa.x, xa.y, xa.z, xa.w, xb.x, xb.y, xb.z, xb.w};
  float lg[8] = {0, 0, 0, 0, 0, 0, 0, 0};
#pragma unroll
  for (int j = 0; j < 8; ++j) {
    const float* wr = Wr + (size_t)(lane * 8 + j) * E_;
    float4 w0 = *reinterpret_cast<const float4*>(wr);
    float4 w1 = *reinterpret_cast<const float4*>(wr + 4);
    lg[0] += xv[j] * w0.x; lg[1] += xv[j] * w0.y; lg[2] += xv[j] * w0.z; lg[3] += xv[j] * w0.w;
    lg[4] += xv[j] * w1.x; lg[5] += xv[j] * w1.y; lg[6] += xv[j] * w1.z; lg[7] += xv[j] * w1.w;
  }
#pragma unroll
  for (int off = 32; off; off >>= 1) {
#pragma unroll
    for (int q = 0; q < 8; ++q) lg[q] += __shfl_xor(lg[q], off);
  }
  if (lane == 0) {
    float m = lg[0];
#pragma unroll
    for (int q = 1; q < 8; ++q) m = fmaxf(m, lg[q]);
    float p[8]; float s = 0.f;
#pragma unroll
    for (int q = 0; q < 8; ++q) { p[q] = expf(lg[q] - m); s += p[q]; }
    float inv = 1.f / s;
    int e1 = 0;
#pragma unroll
    for (int q = 1; q < 8; ++q) if (p[q] > p[e1]) e1 = q;
    int e2 = (e1 == 0) ? 1 : 0;
#pragma unroll
    for (int q = 0; q < 8; ++q) { if (q == e1) continue; if (p[q] > p[e2]) e2 = q; }
    ridx[2 * t] = e1; ridx[2 * t + 1] = e2;
    rw[2 * t] = p[e1] * inv; rw[2 * t + 1] = p[e2] * inv;
  }
}

// single block: counts, 128-padded offsets, zero cursors
__global__ void count_k(const int* __restrict__ ridx, int* __restrict__ ctrl) {
  __shared__ int h[E_];
  const int tid = threadIdx.x;   // 1024
  if (tid < E_) h[tid] = 0;
  __syncthreads();
  int c0=0,c1=0,c2=0,c3=0,c4=0,c5=0,c6=0,c7=0;
  for (int i = tid; i < 2 * N_TOK; i += 1024) {
    int v = ridx[i];
    c0 += (v == 0); c1 += (v == 1); c2 += (v == 2); c3 += (v == 3);
    c4 += (v == 4); c5 += (v == 5); c6 += (v == 6); c7 += (v == 7);
  }
  atomicAdd(&h[0], c0); atomicAdd(&h[1], c1); atomicAdd(&h[2], c2); atomicAdd(&h[3], c3);
  atomicAdd(&h[4], c4); atomicAdd(&h[5], c5); atomicAdd(&h[6], c6); atomicAdd(&h[7], c7);
  __syncthreads();
  if (tid == 0) {
    int a = 0;
    for (int e = 0; e < E_; ++e) {
      ctrl[e] = h[e];
      ctrl[8 + e] = a;
      a += (h[e] + 127) & ~127;
      ctrl[16 + e] = 0;
    }
    ctrl[24] = a;
  }
}

// per-block LDS ranks + 8 global atomics per block
__global__ void scatter_k(const int* __restrict__ ridx, const float* __restrict__ rw,
                          int* __restrict__ ctrl, int* __restrict__ ptok,
                          float* __restrict__ pgate) {
  __shared__ int h[E_], base[E_];
  const int tid = threadIdx.x;                 // 512
  const int g = blockIdx.x * 512 + tid;        // entry id
  if (tid < E_) h[tid] = 0;
  __syncthreads();
  const int e = ridx[g];
  const int r = atomicAdd(&h[e], 1);           // LDS atomic
  __syncthreads();
  if (tid < E_) base[tid] = atomicAdd(&ctrl[16 + tid], h[tid]);
  __syncthreads();
  const int pos = ctrl[8 + e] + base[e] + r;
  ptok[pos] = g >> 1;
  pgate[pos] = rw[g];
}

// gathered activations, FRAGMENT-ORDERED: XpF[sb][kb][64 l][8 j]:
// lane l holds x[tok(sb*16 + (l&15))][kb*32 + (l>>4)*8 + j]. Pad slots -> 0.
__global__ void gather_k(const float* __restrict__ x, const int* __restrict__ ptok,
                         const int* __restrict__ ctrl, unsigned short* __restrict__ XpF) {
  const int sb = blockIdx.x * 4 + (threadIdx.x >> 6);   // slot-block, 4160 total
  const int l  = threadIdx.x & 63;
  const int slot = sb * 16 + (l & 15);
  bool valid = false;
#pragma unroll
  for (int e = 0; e < E_; ++e) {
    int off = ctrl[8 + e], c = ctrl[e];
    valid = valid || (slot >= off && slot < off + c);
  }
  const int tok = valid ? ptok[slot] : 0;
  const int g = l >> 4;
  unsigned short* dst = XpF + ((size_t)sb * 16) * 512 + l * 8;
#pragma unroll
  for (int kb = 0; kb < 16; ++kb) {
    us8 v = (us8){0, 0, 0, 0, 0, 0, 0, 0};
    if (valid) {
      const float* src = x + (size_t)tok * D_ + kb * 32 + g * 8;
      float4 a = *reinterpret_cast<const float4*>(src);
      float4 b = *reinterpret_cast<const float4*>(src + 4);
      v[0] = f2bf(a.x); v[1] = f2bf(a.y); v[2] = f2bf(a.z); v[3] = f2bf(a.w);
      v[4] = f2bf(b.x); v[5] = f2bf(b.y); v[6] = f2bf(b.z); v[7] = f2bf(b.w);
    }
    *reinterpret_cast<us8*>(dst + (size_t)kb * 512) = v;
  }
}

// R13 (best known: 473us) + ONE change: G1 af LDS reads get a 1-kb-ahead
// register rotation (afA/afB) so ds_read latency hides under MFMA issue,
// breaking the in-wave read->MFMA serialization (the residual stall at 2
// waves/SIMD). Register budget: 64+16 AGPR + ~145 VGPR ≈ 225/256 unified.
__global__ __launch_bounds__(512, 2) void ffn_k(
    const unsigned short* __restrict__ XpF,
    const unsigned short* __restrict__ W1F,   // [E][F/16][D/32][64][8]
    const unsigned short* __restrict__ W2B,   // [E][F/32][D/16][64][8]
    const int* __restrict__ ptok, const float* __restrict__ pgate,
    const int* __restrict__ ctrl, float* __restrict__ out) {
  const int gid = blockIdx.x;
  const int e = gid & 7;                      // XCD + expert affinity
  const int cnt = ctrl[e];
  const int tile0 = (gid >> 3) * M_TILE;
  if (tile0 >= cnt) return;
  const int slot0 = ctrl[8 + e] + tile0;      // 64-aligned
  const int sb0 = slot0 >> 4;

  __shared__ unsigned short Xs[32768];        // 64 KB, read-only after prologue
  __shared__ unsigned short Hs[2][8192];      // 2 x 16 KB double buffer

  const int tid = threadIdx.x;
  const int wn = tid >> 6, lane = tid & 63;   // 8 waves = 8 n-slices
  const int lr = lane & 15, lg4 = lane >> 4;

  const unsigned short* w1e = W1F + (size_t)e * (F_ * D_);
  const unsigned short* W2e = W2B + (size_t)e * (F_ * D_);

  // ---- stage X panel once (64 KB linear DMA), overlap initial W1 prefetch
  {
    const char* xsrc = (const char*)(XpF + (size_t)sb0 * 8192);
#pragma unroll
    for (int i = 0; i < 8; ++i) {
      const int o = (i * 512 + tid) * 16;
      gload16(xsrc + o, (char*)Xs + o);
    }
  }
  // initial prefetch: jF=0, kb 0..7 for this wave's f-frag
  bf16x8 bwN[8];
  {
    const unsigned short* w1b0 = w1e + ((size_t)wn * 16) * 512 + lane * 8;
#pragma unroll
    for (int i = 0; i < 8; ++i)
      bwN[i] = *reinterpret_cast<const bf16x8*>(w1b0 + (size_t)i * 512);
  }
  asm volatile("s_waitcnt vmcnt(0)" ::: "memory");
  __builtin_amdgcn_s_barrier();

  f32x4 acc[4][4];                            // [mi rows][ni d-frags]
#pragma unroll
  for (int i = 0; i < 4; ++i)
#pragma unroll
    for (int j = 0; j < 4; ++j) acc[i][j] = {0.f, 0.f, 0.f, 0.f};

  for (int jF = 0; jF < F_; jF += 128) {
    const unsigned short* w1b = w1e + ((size_t)((jF >> 4) + wn) * 16) * 512 + lane * 8;
    const unsigned short* w2b = W2e + ((size_t)((jF >> 5) * 32 + wn * 4)) * 512 + lane * 8;
    unsigned short* hs = Hs[(jF >> 7) & 1];

    f32x4 hacc[4];
#pragma unroll
    for (int i = 0; i < 4; ++i) hacc[i] = {0.f, 0.f, 0.f, 0.f};

    bf16x8 afA[4], afB[4];
    // af prefetch kb=0
#pragma unroll
    for (int mi = 0; mi < 4; ++mi)
      afA[mi] = *reinterpret_cast<const bf16x8*>(&Xs[(mi * 16) * 512 + lane * 8]);

    __builtin_amdgcn_s_setprio(1);
    // issue kb 8..11 (W1)
    bf16x8 bwC[4], bwD[4];
#pragma unroll
    for (int i = 0; i < 4; ++i)
      bwC[i] = *reinterpret_cast<const bf16x8*>(w1b + (size_t)(8 + i) * 512);
    // consume kb 0..3 with af 1-ahead rotation
#pragma unroll
    for (int i = 0; i < 4; ++i) {
#pragma unroll
      for (int mi = 0; mi < 4; ++mi) {
        bf16x8 v = *reinterpret_cast<const bf16x8*>(&Xs[(mi * 16 + i + 1) * 512 + lane * 8]);
        if (i & 1) afA[mi] = v; else afB[mi] = v;
      }
#pragma unroll
      for (int mi = 0; mi < 4; ++mi) {
        bf16x8 a = (i & 1) ? afB[mi] : afA[mi];
        hacc[mi] = __builtin_amdgcn_mfma_f32_16x16x32_bf16(a, bwN[i], hacc[mi], 0, 0, 0);
      }
    }
    // issue kb 12..15 (W1)
#pragma unroll
    for (int i = 0; i < 4; ++i)
      bwD[i] = *reinterpret_cast<const bf16x8*>(w1b + (size_t)(12 + i) * 512);
    // consume kb 4..7
#pragma unroll
    for (int i = 0; i < 4; ++i) {
      const int kb = 4 + i;
#pragma unroll
      for (int mi = 0; mi < 4; ++mi) {
        bf16x8 v = *reinterpret_cast<const bf16x8*>(&Xs[(mi * 16 + kb + 1) * 512 + lane * 8]);
        if (kb & 1) afA[mi] = v; else afB[mi] = v;
      }
#pragma unroll
      for (int mi = 0; mi < 4; ++mi) {
        bf16x8 a = (kb & 1) ? afB[mi] : afA[mi];
        hacc[mi] = __builtin_amdgcn_mfma_f32_16x16x32_bf16(a, bwN[4 + i], hacc[mi], 0, 0, 0);
      }
    }
    // issue GEMM2 kf=0 group
    bf16x8 b2A[4], b2B[4];
#pragma unroll
    for (int i = 0; i < 4; ++i)
      b2A[i] = *reinterpret_cast<const bf16x8*>(w2b + (size_t)i * 512);
    // consume kb 8..11
#pragma unroll
    for (int i = 0; i < 4; ++i) {
      const int kb = 8 + i;
#pragma unroll
      for (int mi = 0; mi < 4; ++mi) {
        bf16x8 v = *reinterpret_cast<const bf16x8*>(&Xs[(mi * 16 + kb + 1) * 512 + lane * 8]);
        if (kb & 1) afA[mi] = v; else afB[mi] = v;
      }
#pragma unroll
      for (int mi = 0; mi < 4; ++mi) {
        bf16x8 a = (kb & 1) ? afB[mi] : afA[mi];
        hacc[mi] = __builtin_amdgcn_mfma_f32_16x16x32_bf16(a, bwC[i], hacc[mi], 0, 0, 0);
      }
    }
    // issue GEMM2 kf=1 group
#pragma unroll
    for (int i = 0; i < 4; ++i)
      b2B[i] = *reinterpret_cast<const bf16x8*>(w2b + (size_t)(16384 + i * 512));
    // consume kb 12..15 (kb+1 read clamped at 15)
#pragma unroll
    for (int i = 0; i < 4; ++i) {
      const int kb = 12 + i;
      if (i < 3) {
#pragma unroll
        for (int mi = 0; mi < 4; ++mi) {
          bf16x8 v = *reinterpret_cast<const bf16x8*>(&Xs[(mi * 16 + kb + 1) * 512 + lane * 8]);
          if (kb & 1) afA[mi] = v; else afB[mi] = v;
        }
      }
#pragma unroll
      for (int mi = 0; mi < 4; ++mi) {
        bf16x8 a = (kb & 1) ? afB[mi] : afA[mi];
        hacc[mi] = __builtin_amdgcn_mfma_f32_16x16x32_bf16(a, bwD[i], hacc[mi], 0, 0, 0);
      }
    }
    __builtin_amdgcn_s_setprio(0);

    // ---- fast GELU -> Hs[buf] (bf16), 16B-chunk XOR swizzle
#pragma unroll
    for (int mi = 0; mi < 4; ++mi)
#pragma unroll
      for (int r = 0; r < 4; ++r) {
        float v = hacc[mi][r];
        float u = v * v;
        float wv = v * fmaf(0.044715f, u, 1.0f);
        float z = __expf(-1.5957691216057308f * wv);
        float g = v * __builtin_amdgcn_rcpf(1.0f + z);
        const int row = mi * 16 + lg4 * 4 + r;
        const int col = wn * 16 + lr;
        const int ch = (col >> 3) ^ (row & 15);
        hs[row * 128 + ch * 8 + (col & 7)] = f2bf(g);
      }

    // ---- prefetch NEXT jF's W1 kb0..7: rides across barrier + GEMM2
    if (jF < F_ - 128) {
      const unsigned short* w1n = w1b + 65536;   // fb += 8
#pragma unroll
      for (int i = 0; i < 8; ++i)
        bwN[i] = *reinterpret_cast<const bf16x8*>(w1n + (size_t)i * 512);
    }

    lbar();   // Hs[buf] writes visible; vmcnt NOT drained

    // ---- GEMM2: A from Hs[buf] (swizzled), B 1 kf-group ahead
    __builtin_amdgcn_s_setprio(1);
#pragma unroll
    for (int kf = 0; kf < 4; ++kf) {
      bf16x8 bcur[4];
#pragma unroll
      for (int i = 0; i < 4; ++i) bcur[i] = (kf & 1) ? b2B[i] : b2A[i];
      if (kf < 2) {
#pragma unroll
        for (int i = 0; i < 4; ++i) {
          bf16x8 nv = *reinterpret_cast<const bf16x8*>(w2b + (size_t)((kf + 2) * 16384 + i * 512));
          if (kf & 1) b2B[i] = nv; else b2A[i] = nv;
        }
      }
      bf16x8 ah[4];
#pragma unroll
      for (int mi = 0; mi < 4; ++mi) {
        const int row = mi * 16 + lr;
        const int ch = (kf * 4 + lg4) ^ (row & 15);
        ah[mi] = *reinterpret_cast<const bf16x8*>(&hs[row * 128 + ch * 8]);
      }
#pragma unroll
      for (int mi = 0; mi < 4; ++mi)
#pragma unroll
        for (int ni = 0; ni < 4; ++ni)
          acc[mi][ni] = __builtin_amdgcn_mfma_f32_16x16x32_bf16(ah[mi], bcur[ni], acc[mi][ni], 0, 0, 0);
    }
    __builtin_amdgcn_s_setprio(0);
    // no second barrier: next jF's GELU writes the OTHER Hs buffer
  }

  // ---- epilogue: gate from global, atomic-add (exactly 2 adds/elem -> deterministic)
  const int rowLim = cnt - tile0;
#pragma unroll
  for (int mi = 0; mi < 4; ++mi) {
#pragma unroll
    for (int r = 0; r < 4; ++r) {
      const int row = mi * 16 + lg4 * 4 + r;
      if (row < rowLim) {
        const int tok = ptok[slot0 + row];
        const float gt = pgate[slot0 + row];
        float* orow = out + (size_t)tok * D_ + wn * 64 + lr;
#pragma unroll
        for (int ni = 0; ni < 4; ++ni)
          atomicAdd(orow + ni * 16, gt * acc[mi][ni][r]);
      }
    }
  }
}

extern "C" void kernel_launch(void* const* d_in, const int* in_sizes, int n_in,
                              void* d_out, int out_size, void* d_ws, size_t ws_size,
                              hipStream_t stream) {
  const float* x  = (const float*)d_in[0];
  const float* Wr = (const float*)d_in[1];
  const float* W1 = (const float*)d_in[2];
  const float* W2 = (const float*)d_in[3];
  float* out = (float*)d_out;

  char* w = (char*)d_ws;
  unsigned short* W1F = (unsigned short*)(w);                    // 16 MiB frag-ordered
  unsigned short* W2B = (unsigned short*)(w + 16777216);         // 16 MiB frag-ordered
  unsigned short* XpF = (unsigned short*)(w + 33554432);         // 65 MiB frag-ordered
  int*   ridx  = (int*)  (w + 101711872);
  float* rwgt  = (float*)(w + 101974016);
  int*   ptok  = (int*)  (w + 102236160);
  float* pgate = (float*)(w + 102502400);
  int*   ctrl  = (int*)  (w + 102768640);

  cvtW12_k<<<8192, 256, 0, stream>>>(W1, W1F, W2, W2B);
  router_k<<<N_TOK / 4, 256, 0, stream>>>(x, Wr, ridx, rwgt);
  count_k<<<1, 1024, 0, stream>>>(ridx, ctrl);
  scatter_k<<<N_TOK * 2 / 512, 512, 0, stream>>>(ridx, rwgt, ctrl, ptok, pgate);
  gather_k<<<NSLOT_MAX / 16 / 4, 256, 0, stream>>>(x, ptok, ctrl, XpF);
  hipMemsetAsync(out, 0, (size_t)out_size * sizeof(float), stream);
  ffn_k<<<8192, 512, 0, stream>>>(XpF, W1F, W2B, ptok, pgate, ctrl, out);
}